// Round 4
// baseline (168.834 us; speedup 1.0000x reference)
//
#include <hip/hip_runtime.h>
#include <hip/hip_bf16.h>
#include <stdint.h>

// Problem constants (fixed by setup_inputs)
#define T_SEQ  2048
#define DMODEL 1024
#define NBATCH 2
#define NHEAD  16
#define DHEAD  64
#define MTOT   (NBATCH * T_SEQ)   // 4096 rows for all projection GEMMs

typedef __attribute__((ext_vector_type(8))) short short8_t;  // 8 bf16 (4 VGPRs) MFMA A/B frag
typedef __attribute__((ext_vector_type(4))) float f32x4;     // MFMA C/D frag

typedef const __attribute__((address_space(1))) void* gas_t;
typedef __attribute__((address_space(3))) void* las_t;

__device__ __forceinline__ ushort f2bf(float f) {
    union { float f; uint32_t u; } cv; cv.f = f;
    uint32_t u = cv.u;
    return (ushort)((u + 0x7FFFu + ((u >> 16) & 1u)) >> 16);  // RNE
}

// ---------------- fp32 -> bf16 convert of q,k,v into one contiguous [3][4096][1024] ----------------
__global__ __launch_bounds__(256) void convert_qkv_kernel(
        const float* __restrict__ q, const float* __restrict__ k,
        const float* __restrict__ v, ushort* __restrict__ outb) {
    const size_t per = (size_t)MTOT * DMODEL / 4;           // float4s per tensor = 1048576
    size_t idx = (size_t)blockIdx.x * 256 + threadIdx.x;
    int t = (int)(idx / per);
    size_t i = idx - (size_t)t * per;
    const float4* src = (const float4*)(t == 0 ? q : (t == 1 ? k : v));
    float4 val = src[i];
    ushort4 o;
    o.x = f2bf(val.x); o.y = f2bf(val.y); o.z = f2bf(val.z); o.w = f2bf(val.w);
    ((ushort4*)outb)[(size_t)t * per + i] = o;
}

// ---- W fp32 [K][N] -> bf16 transposed [N][K]; Wq gets 1/sqrt(dk)*log2(e) folded in (exp2 domain) --
__global__ __launch_bounds__(256) void convw_kernel(
        const float* __restrict__ Wq, const float* __restrict__ Wk,
        const float* __restrict__ Wv, const float* __restrict__ Wo,
        ushort* __restrict__ wt) {
    __shared__ float tile[32][33];                          // +1 pad: conflict-free transpose
    int z = blockIdx.z;
    const float* W = z == 0 ? Wq : z == 1 ? Wk : z == 2 ? Wv : Wo;
    const float sc = (z == 0) ? 0.18033688011f : 1.0f;      // 0.125 * log2(e)
    ushort* out = wt + (size_t)z * DMODEL * DMODEL;
    int tx = threadIdx.x, ty = threadIdx.y;                 // 32 x 8
    int k0 = blockIdx.x * 32, n0 = blockIdx.y * 32;
    #pragma unroll
    for (int i = 0; i < 4; i++)
        tile[ty + i * 8][tx] = W[(size_t)(k0 + ty + i * 8) * DMODEL + n0 + tx];
    __syncthreads();
    #pragma unroll
    for (int i = 0; i < 4; i++)
        out[(size_t)(n0 + ty + i * 8) * DMODEL + k0 + tx] = f2bf(tile[tx][ty + i * 8] * sc);
}

// ---------------- bf16 GEMM, m97 structure: C[M][N] = A[M][K] * Bt[N][K]^T ----------------
// 128x128 tile, BK=32, 4 waves (2x2), 4x4 16x16x32 MFMA accs per wave, global_load_lds(16B) staging.
template <bool OUT_F32>
__global__ __launch_bounds__(256, 2) void gemm_bt_kernel(
        const ushort* __restrict__ Aall, const ushort* __restrict__ Btall,
        void* __restrict__ Call, int M, int N, int K) {
    const ushort* A  = Aall  + (size_t)blockIdx.z * M * K;
    const ushort* Bt = Btall + (size_t)blockIdx.z * N * K;

    __shared__ ushort As[128 * 32];   // [128 rows][32 k] row-major, 8 KB
    __shared__ ushort Bs[128 * 32];

    const int tid  = threadIdx.x;
    const int lane = tid & 63;
    const int wid  = tid >> 6;
    const int wr = wid >> 1, wc = wid & 1;          // 2x2 wave grid, 64x64 out each
    const int m_base = blockIdx.x * 128;
    const int n_base = blockIdx.y * 128;

    f32x4 acc[4][4] = {};

    const int srow = lane >> 2;                     // staging: 16 rows / chunk
    const int scol = (lane & 3) * 8;                // 4 x 16B per row

    for (int kk = 0; kk < K; kk += 32) {
        __syncthreads();                            // prior tile's reads complete
        #pragma unroll
        for (int i = 0; i < 2; i++) {
            int c = wid * 2 + i;                    // 8 x 1KB chunks each for A and B
            const ushort* ga = A  + (size_t)(m_base + c * 16 + srow) * K + kk + scol;
            const ushort* gb = Bt + (size_t)(n_base + c * 16 + srow) * K + kk + scol;
            __builtin_amdgcn_global_load_lds((gas_t)ga, (las_t)(As + c * 512), 16, 0, 0);
            __builtin_amdgcn_global_load_lds((gas_t)gb, (las_t)(Bs + c * 512), 16, 0, 0);
        }
        __syncthreads();                            // drains vmcnt -> staged data visible
        short8_t a[4], b[4];
        #pragma unroll
        for (int mt = 0; mt < 4; mt++)
            a[mt] = *(const short8_t*)(As + (wr * 64 + mt * 16 + (lane & 15)) * 32 + (lane >> 4) * 8);
        #pragma unroll
        for (int nt = 0; nt < 4; nt++)
            b[nt] = *(const short8_t*)(Bs + (wc * 64 + nt * 16 + (lane & 15)) * 32 + (lane >> 4) * 8);
        #pragma unroll
        for (int mt = 0; mt < 4; mt++)
            #pragma unroll
            for (int nt = 0; nt < 4; nt++)
                acc[mt][nt] = __builtin_amdgcn_mfma_f32_16x16x32_bf16(a[mt], b[nt], acc[mt][nt], 0, 0, 0);
    }

    // Epilogue: D layout col = lane&15, row = (lane>>4)*4 + r  [verified m89/m91]
    const int row0 = m_base + wr * 64 + (lane >> 4) * 4;
    const int col0 = n_base + wc * 64 + (lane & 15);
    if constexpr (OUT_F32) {
        float* C = (float*)Call + (size_t)blockIdx.z * M * N;
        #pragma unroll
        for (int mt = 0; mt < 4; mt++)
            #pragma unroll
            for (int nt = 0; nt < 4; nt++)
                #pragma unroll
                for (int r = 0; r < 4; r++)
                    C[(size_t)(row0 + mt * 16 + r) * N + col0 + nt * 16] = acc[mt][nt][r];
    } else {
        ushort* C = (ushort*)Call + (size_t)blockIdx.z * M * N;
        #pragma unroll
        for (int mt = 0; mt < 4; mt++)
            #pragma unroll
            for (int nt = 0; nt < 4; nt++)
                #pragma unroll
                for (int r = 0; r < 4; r++)
                    C[(size_t)(row0 + mt * 16 + r) * N + col0 + nt * 16] = f2bf(acc[mt][nt][r]);
    }
}

// ---------------- causal flash attention, 2-wave blocks, dbuf, 1 barrier/tile ----------------
// grid = (32 pairs, 32 b*h) = 1024 blocks, 128 threads (2 waves). QBLK=32: block does q-blocks
// qa and 63-qa -> exactly 33 KV-64 tiles. Each wave owns 16 q-rows. K/V double-buffered in LDS
// (XOR-swizzled, unpadded): iter t = {barrier; write t+1; load t+2; compute t}. Softmax in exp2
// domain (scale*log2e folded into Wq), T13 defer-max, T5 setprio. 37.4KB LDS -> 4 blocks/CU.
__global__ __launch_bounds__(128, 2) void attn_kernel(
        const ushort* __restrict__ Qp, const ushort* __restrict__ Kp,
        const ushort* __restrict__ Vp, ushort* __restrict__ Op) {
    __shared__ __attribute__((aligned(16))) ushort Ksh[2][64 * 64];  // [kv][dk] swizzled
    __shared__ __attribute__((aligned(16))) ushort Vts[2][64 * 64];  // [dv][kv] swizzled
    __shared__ __attribute__((aligned(16))) ushort Psh[2][16 * 72];  // per-wave P, padded

    const int tid = threadIdx.x, lane = tid & 63, w = tid >> 6;
    const int g = lane >> 4, m = lane & 15;
    const int xo = (m & 7) * 8;            // frag-read XOR (ushort units)
    const int bh = blockIdx.y;
    const int b = bh >> 4, h = bh & 15;

    const ushort* Qb = Qp + (size_t)(b * T_SEQ) * DMODEL + h * DHEAD;
    const ushort* Kb = Kp + (size_t)(b * T_SEQ) * DMODEL + h * DHEAD;
    const ushort* Vb = Vp + (size_t)(b * T_SEQ) * DMODEL + h * DHEAD;
    ushort* Ob = Op + (size_t)(b * T_SEQ) * DMODEL + h * DHEAD;

    const int qa = blockIdx.x;             // 0..31
    const int qiB = 63 - qa;
    const int na = (qa >> 1) + 1;          // tiles in half A (half B: (qiB>>1)+1; total 33)

    // staging decomposition (128 threads)
    const int kr = tid >> 3, kslot = tid & 7;        // K: rows kr+16i, 16B slot kslot
    const int ksw = (kslot ^ (kr & 7)) * 8;          // swizzled ushort offset in row
    const int kvq = tid & 15, dvc = tid >> 4;        // V: kv quad, dv octet (0..7)

    short8_t kk[4], vv[4];
    auto LOADKV = [&](int kv0) {
        #pragma unroll
        for (int i = 0; i < 4; i++)
            kk[i] = *(const short8_t*)(Kb + (size_t)(kv0 + kr + 16 * i) * DMODEL + kslot * 8);
        #pragma unroll
        for (int i = 0; i < 4; i++)
            vv[i] = *(const short8_t*)(Vb + (size_t)(kv0 + kvq * 4 + i) * DMODEL + dvc * 8);
    };
    auto WRITEKV = [&](int buf) {
        #pragma unroll
        for (int i = 0; i < 4; i++)
            *(short8_t*)(&Ksh[buf][(kr + 16 * i) * 64 + ksw]) = kk[i];
        #pragma unroll
        for (int dd = 0; dd < 8; dd++) {             // V transposed: row d = dvc*8+dd
            uint32_t lo = (uint32_t)(ushort)vv[0][dd] | ((uint32_t)(ushort)vv[1][dd] << 16);
            uint32_t hi = (uint32_t)(ushort)vv[2][dd] | ((uint32_t)(ushort)vv[3][dd] << 16);
            uint2 pk; pk.x = lo; pk.y = hi;
            *(uint2*)(&Vts[buf][(dvc * 8 + dd) * 64 + (((kvq >> 1) ^ dd) * 8) + (kvq & 1) * 4]) = pk;
        }
    };

    int qi = qa, q0 = qa * 32;
    short8_t qf[2];
    #pragma unroll
    for (int kc = 0; kc < 2; kc++)
        qf[kc] = *(const short8_t*)(Qb + (size_t)(q0 + w * 16 + m) * DMODEL + kc * 32 + g * 8);

    f32x4 acc_o[4] = {};                   // O[q 16][dv 64] per wave
    float mrun = -1e30f, lrun = 0.f;
    ushort* Pw = Psh[w];

    auto WRITE_O = [&]() {
        #pragma unroll
        for (int r = 0; r < 4; r++) {
            float linv = 1.f / __shfl(lrun, g * 4 + r);
            int qrow = q0 + w * 16 + g * 4 + r;
            #pragma unroll
            for (int dt = 0; dt < 4; dt++)
                Ob[(size_t)qrow * DMODEL + dt * 16 + m] = f2bf(acc_o[dt][r] * linv);
        }
    };
    auto TILE = [&](int t) { return (t < na) ? t : t - na; };

    LOADKV(TILE(0) * 64);
    WRITEKV(0);
    LOADKV(TILE(1) * 64);

    for (int tt = 0; tt < 33; ++tt) {
        if (tt == na) {                    // half boundary: finish A, start B
            WRITE_O();
            #pragma unroll
            for (int dt = 0; dt < 4; dt++) acc_o[dt] = f32x4{0.f, 0.f, 0.f, 0.f};
            mrun = -1e30f; lrun = 0.f;
            qi = qiB; q0 = qi * 32;
            #pragma unroll
            for (int kc = 0; kc < 2; kc++)
                qf[kc] = *(const short8_t*)(Qb + (size_t)(q0 + w * 16 + m) * DMODEL + kc * 32 + g * 8);
        }
        const int t = TILE(tt);
        const int kv0 = t * 64;
        const bool need_mask = (t == (qi >> 1));
        const int cur = tt & 1;

        __syncthreads();                   // tile tt's writes (from iter tt-1) complete
        if (tt + 1 < 33) {
            WRITEKV(cur ^ 1);              // stage tile tt+1 into other buffer
            if (tt + 2 < 33) LOADKV(TILE(tt + 2) * 64);
        }

        // S^T = K * Q^T : lane holds S^T[kv = kvT*16 + g*4 + r][q = m]   (exp2-domain scores)
        f32x4 s[4] = {};
        __builtin_amdgcn_s_setprio(1);
        #pragma unroll
        for (int kvT = 0; kvT < 4; kvT++)
            #pragma unroll
            for (int kc = 0; kc < 2; kc++) {
                short8_t kf = *(const short8_t*)(&Ksh[cur][(kvT * 16 + m) * 64 + ((kc * 32 + g * 8) ^ xo)]);
                s[kvT] = __builtin_amdgcn_mfma_f32_16x16x32_bf16(kf, qf[kc], s[kvT], 0, 0, 0);
            }
        __builtin_amdgcn_s_setprio(0);

        // causal mask (diagonal tile only) + tile max
        const int qg = q0 + w * 16 + m;
        float pmax = -1e30f;
        #pragma unroll
        for (int kvT = 0; kvT < 4; kvT++)
            #pragma unroll
            for (int r = 0; r < 4; r++) {
                float val = s[kvT][r];
                if (need_mask) {
                    int kv_g = kv0 + kvT * 16 + g * 4 + r;
                    if (kv_g > qg) val = -1e30f;
                }
                s[kvT][r] = val;
                pmax = fmaxf(pmax, val);
            }
        pmax = fmaxf(pmax, __shfl_xor(pmax, 16));
        pmax = fmaxf(pmax, __shfl_xor(pmax, 32));
        if (!__all(pmax <= mrun + 8.f)) {  // T13 defer-max: rescale only on real max growth
            float mnew = fmaxf(mrun, pmax);
            float fac = exp2f(mrun - mnew);
            mrun = mnew;
            lrun *= fac;
            #pragma unroll
            for (int r = 0; r < 4; r++) {
                float f = __shfl(fac, g * 4 + r);
                #pragma unroll
                for (int dt = 0; dt < 4; dt++) acc_o[dt][r] *= f;
            }
        }
        float psum = 0.f;
        #pragma unroll
        for (int kvT = 0; kvT < 4; kvT++)
            #pragma unroll
            for (int r = 0; r < 4; r++) {
                float p = exp2f(s[kvT][r] - mrun);
                s[kvT][r] = p;
                psum += p;
            }
        psum += __shfl_xor(psum, 16);
        psum += __shfl_xor(psum, 32);
        lrun += psum;

        // P (bf16, <=2^8) -> wave-private LDS (same-wave write->read, lgkmcnt-ordered)
        #pragma unroll
        for (int kvT = 0; kvT < 4; kvT++) {
            uint32_t lo = (uint32_t)f2bf(s[kvT][0]) | ((uint32_t)f2bf(s[kvT][1]) << 16);
            uint32_t hi = (uint32_t)f2bf(s[kvT][2]) | ((uint32_t)f2bf(s[kvT][3]) << 16);
            uint2 pk; pk.x = lo; pk.y = hi;
            *(uint2*)(Pw + m * 72 + kvT * 16 + g * 4) = pk;
        }

        // O += P * V
        short8_t pf[2];
        #pragma unroll
        for (int kc = 0; kc < 2; kc++)
            pf[kc] = *(const short8_t*)(Pw + m * 72 + kc * 32 + g * 8);
        __builtin_amdgcn_s_setprio(1);
        #pragma unroll
        for (int dt = 0; dt < 4; dt++)
            #pragma unroll
            for (int kc = 0; kc < 2; kc++) {
                short8_t vf = *(const short8_t*)(&Vts[cur][(dt * 16 + m) * 64 + ((kc * 32 + g * 8) ^ xo)]);
                acc_o[dt] = __builtin_amdgcn_mfma_f32_16x16x32_bf16(pf[kc], vf, acc_o[dt], 0, 0, 0);
            }
        __builtin_amdgcn_s_setprio(0);
    }
    WRITE_O();
}

// ---------------- launch ----------------
extern "C" void kernel_launch(void* const* d_in, const int* in_sizes, int n_in,
                              void* d_out, int out_size, void* d_ws, size_t ws_size,
                              hipStream_t stream) {
    (void)in_sizes; (void)n_in; (void)out_size; (void)ws_size;
    const float* q  = (const float*)d_in[0];
    const float* k  = (const float*)d_in[1];
    const float* v  = (const float*)d_in[2];
    // d_in[3] = mask (causal tril) -- implemented analytically
    const float* Wq = (const float*)d_in[4];
    const float* Wk = (const float*)d_in[5];
    const float* Wv = (const float*)d_in[6];
    const float* Wo = (const float*)d_in[7];

    ushort* ws = (ushort*)d_ws;
    const size_t MK = (size_t)MTOT * DMODEL;    // 4194304 elems
    const size_t NK = (size_t)DMODEL * DMODEL;  // 1048576 elems
    ushort* qkvb = ws;                    // bf16 q,k,v        [3*MK]   (24 MB)
    ushort* wt   = ws + 3 * MK;           // bf16 W^T x4       [4*NK]   ( 8 MB)
    ushort* qkvp = ws + 3 * MK + 4 * NK;  // bf16 Q,K,V proj   [3*MK]   (24 MB)
    ushort* Op   = ws;                    // attn out reuses qkvb region ( 8 MB)
    // total ws footprint: 56 MB

    convert_qkv_kernel<<<dim3(12288), dim3(256), 0, stream>>>(q, k, v, qkvb);
    convw_kernel<<<dim3(32, 32, 4), dim3(32, 8), 0, stream>>>(Wq, Wk, Wv, Wo, wt);
    gemm_bt_kernel<false><<<dim3(32, 8, 3), dim3(256), 0, stream>>>(qkvb, wt, (void*)qkvp,
                                                                    MTOT, DMODEL, DMODEL);
    attn_kernel<<<dim3(32, 32), dim3(128), 0, stream>>>(qkvp, qkvp + MK, qkvp + 2 * MK, Op);
    gemm_bt_kernel<true><<<dim3(32, 8, 1), dim3(256), 0, stream>>>(Op, wt + 3 * NK, d_out,
                                                                   MTOT, DMODEL, DMODEL);
}

// Round 5
// 138.211 us; speedup vs baseline: 1.2216x; 1.2216x over previous
//
#include <hip/hip_runtime.h>
#include <hip/hip_bf16.h>
#include <stdint.h>

// Problem constants (fixed by setup_inputs)
#define T_SEQ  2048
#define DMODEL 1024
#define NBATCH 2
#define NHEAD  16
#define DHEAD  64
#define MTOT   (NBATCH * T_SEQ)   // 4096 rows for all projection GEMMs

typedef __attribute__((ext_vector_type(8))) short short8_t;  // 8 bf16 (4 VGPRs) MFMA A/B frag
typedef __attribute__((ext_vector_type(4))) float f32x4;     // MFMA C/D frag

typedef const __attribute__((address_space(1))) void* gas_t;
typedef __attribute__((address_space(3))) void* las_t;

__device__ __forceinline__ ushort f2bf(float f) {
    union { float f; uint32_t u; } cv; cv.f = f;
    uint32_t u = cv.u;
    return (ushort)((u + 0x7FFFu + ((u >> 16) & 1u)) >> 16);  // RNE
}

// ---------------- fp32 -> bf16 convert of q,k,v into one contiguous [3][4096][1024] ----------------
__global__ __launch_bounds__(256) void convert_qkv_kernel(
        const float* __restrict__ q, const float* __restrict__ k,
        const float* __restrict__ v, ushort* __restrict__ outb) {
    const size_t per = (size_t)MTOT * DMODEL / 4;           // float4s per tensor = 1048576
    size_t idx = (size_t)blockIdx.x * 256 + threadIdx.x;
    int t = (int)(idx / per);
    size_t i = idx - (size_t)t * per;
    const float4* src = (const float4*)(t == 0 ? q : (t == 1 ? k : v));
    float4 val = src[i];
    ushort4 o;
    o.x = f2bf(val.x); o.y = f2bf(val.y); o.z = f2bf(val.z); o.w = f2bf(val.w);
    ((ushort4*)outb)[(size_t)t * per + i] = o;
}

// ---- W fp32 [K][N] -> bf16 transposed [N][K]; Wq gets 1/sqrt(dk)*log2(e) folded in (exp2 domain) --
__global__ __launch_bounds__(256) void convw_kernel(
        const float* __restrict__ Wq, const float* __restrict__ Wk,
        const float* __restrict__ Wv, const float* __restrict__ Wo,
        ushort* __restrict__ wt) {
    __shared__ float tile[32][33];                          // +1 pad: conflict-free transpose
    int z = blockIdx.z;
    const float* W = z == 0 ? Wq : z == 1 ? Wk : z == 2 ? Wv : Wo;
    const float sc = (z == 0) ? 0.18033688011f : 1.0f;      // 0.125 * log2(e)
    ushort* out = wt + (size_t)z * DMODEL * DMODEL;
    int tx = threadIdx.x, ty = threadIdx.y;                 // 32 x 8
    int k0 = blockIdx.x * 32, n0 = blockIdx.y * 32;
    #pragma unroll
    for (int i = 0; i < 4; i++)
        tile[ty + i * 8][tx] = W[(size_t)(k0 + ty + i * 8) * DMODEL + n0 + tx];
    __syncthreads();
    #pragma unroll
    for (int i = 0; i < 4; i++)
        out[(size_t)(n0 + ty + i * 8) * DMODEL + k0 + tx] = f2bf(tile[tx][ty + i * 8] * sc);
}

// ---------------- bf16 GEMM, m97 structure: C[M][N] = A[M][K] * Bt[N][K]^T ----------------
// 128x128 tile, BK=32, 4 waves (2x2), 4x4 16x16x32 MFMA accs per wave, global_load_lds(16B) staging.
template <bool OUT_F32>
__global__ __launch_bounds__(256, 2) void gemm_bt_kernel(
        const ushort* __restrict__ Aall, const ushort* __restrict__ Btall,
        void* __restrict__ Call, int M, int N, int K) {
    const ushort* A  = Aall  + (size_t)blockIdx.z * M * K;
    const ushort* Bt = Btall + (size_t)blockIdx.z * N * K;

    __shared__ ushort As[128 * 32];   // [128 rows][32 k] row-major, 8 KB
    __shared__ ushort Bs[128 * 32];

    const int tid  = threadIdx.x;
    const int lane = tid & 63;
    const int wid  = tid >> 6;
    const int wr = wid >> 1, wc = wid & 1;          // 2x2 wave grid, 64x64 out each
    const int m_base = blockIdx.x * 128;
    const int n_base = blockIdx.y * 128;

    f32x4 acc[4][4] = {};

    const int srow = lane >> 2;                     // staging: 16 rows / chunk
    const int scol = (lane & 3) * 8;                // 4 x 16B per row

    for (int kk = 0; kk < K; kk += 32) {
        __syncthreads();                            // prior tile's reads complete
        #pragma unroll
        for (int i = 0; i < 2; i++) {
            int c = wid * 2 + i;                    // 8 x 1KB chunks each for A and B
            const ushort* ga = A  + (size_t)(m_base + c * 16 + srow) * K + kk + scol;
            const ushort* gb = Bt + (size_t)(n_base + c * 16 + srow) * K + kk + scol;
            __builtin_amdgcn_global_load_lds((gas_t)ga, (las_t)(As + c * 512), 16, 0, 0);
            __builtin_amdgcn_global_load_lds((gas_t)gb, (las_t)(Bs + c * 512), 16, 0, 0);
        }
        __syncthreads();                            // drains vmcnt -> staged data visible
        short8_t a[4], b[4];
        #pragma unroll
        for (int mt = 0; mt < 4; mt++)
            a[mt] = *(const short8_t*)(As + (wr * 64 + mt * 16 + (lane & 15)) * 32 + (lane >> 4) * 8);
        #pragma unroll
        for (int nt = 0; nt < 4; nt++)
            b[nt] = *(const short8_t*)(Bs + (wc * 64 + nt * 16 + (lane & 15)) * 32 + (lane >> 4) * 8);
        #pragma unroll
        for (int mt = 0; mt < 4; mt++)
            #pragma unroll
            for (int nt = 0; nt < 4; nt++)
                acc[mt][nt] = __builtin_amdgcn_mfma_f32_16x16x32_bf16(a[mt], b[nt], acc[mt][nt], 0, 0, 0);
    }

    // Epilogue: D layout col = lane&15, row = (lane>>4)*4 + r  [verified m89/m91]
    const int row0 = m_base + wr * 64 + (lane >> 4) * 4;
    const int col0 = n_base + wc * 64 + (lane & 15);
    if constexpr (OUT_F32) {
        float* C = (float*)Call + (size_t)blockIdx.z * M * N;
        #pragma unroll
        for (int mt = 0; mt < 4; mt++)
            #pragma unroll
            for (int nt = 0; nt < 4; nt++)
                #pragma unroll
                for (int r = 0; r < 4; r++)
                    C[(size_t)(row0 + mt * 16 + r) * N + col0 + nt * 16] = acc[mt][nt][r];
    } else {
        ushort* C = (ushort*)Call + (size_t)blockIdx.z * M * N;
        #pragma unroll
        for (int mt = 0; mt < 4; mt++)
            #pragma unroll
            for (int nt = 0; nt < 4; nt++)
                #pragma unroll
                for (int r = 0; r < 4; r++)
                    C[(size_t)(row0 + mt * 16 + r) * N + col0 + nt * 16] = f2bf(acc[mt][nt][r]);
    }
}

// ---------------- causal flash attention, balanced pairs + dbuf (1 barrier/tile) ----------------
// grid = (16 pairs, 32 b*h) = 512 blocks, 4 waves. Block does q-blocks qa and 31-qa (QBLK=64):
// exactly 33 KV-tiles. Each wave owns 16 q-rows. K/V double-buffered in LDS (pad-72):
// iter tt = {barrier; ds-write tile tt+1; global-load tile tt+2; compute tile tt}.
// exp2-domain softmax (scale*log2e folded into Wq), T13 defer-max, T5 setprio.
__global__ __launch_bounds__(256, 2) void attn_kernel(
        const ushort* __restrict__ Qp, const ushort* __restrict__ Kp,
        const ushort* __restrict__ Vp, ushort* __restrict__ Op) {
    __shared__ __attribute__((aligned(16))) ushort Ksh[2][64 * 72];  // [kv][dk], 144B rows
    __shared__ __attribute__((aligned(16))) ushort Vts[2][64 * 72];  // [dv][kv] transposed
    __shared__ __attribute__((aligned(16))) ushort Psh[4][16 * 72];  // per-wave P [16 q][64 kv]

    const int tid = threadIdx.x, lane = tid & 63, w = tid >> 6;
    const int g = lane >> 4;               // 4 lane-groups of 16
    const int m = lane & 15;
    const int bh = blockIdx.y;
    const int b = bh >> 4, h = bh & 15;

    const ushort* Qb = Qp + (size_t)(b * T_SEQ) * DMODEL + h * DHEAD;
    const ushort* Kb = Kp + (size_t)(b * T_SEQ) * DMODEL + h * DHEAD;
    const ushort* Vb = Vp + (size_t)(b * T_SEQ) * DMODEL + h * DHEAD;
    ushort* Ob = Op + (size_t)(b * T_SEQ) * DMODEL + h * DHEAD;

    const int qa = blockIdx.x;             // first (light) q-block
    const int na = qa + 1;                 // tiles for half A; half B: 31-qa -> 32-qa tiles

    // staging decomposition (256 threads)
    const int kr  = tid >> 3, kck = (tid & 7) * 8;   // K: rows kr, kr+32; 16B col chunk
    const int kvp = tid & 31, dvc = tid >> 5;        // V: kv pair, dv 8-chunk

    short8_t kreg0, kreg1, vreg0, vreg1;             // prefetched K/V tile (16 VGPRs)
    auto LOADKV = [&](int kv0) {
        kreg0 = *(const short8_t*)(Kb + (size_t)(kv0 + kr) * DMODEL + kck);
        kreg1 = *(const short8_t*)(Kb + (size_t)(kv0 + kr + 32) * DMODEL + kck);
        const ushort* vsrc = Vb + (size_t)(kv0 + kvp * 2) * DMODEL + dvc * 8;
        vreg0 = *(const short8_t*)(vsrc);
        vreg1 = *(const short8_t*)(vsrc + DMODEL);
    };
    auto WRITEKV = [&](int buf) {
        *(short8_t*)(&Ksh[buf][kr * 72 + kck]) = kreg0;
        *(short8_t*)(&Ksh[buf][(kr + 32) * 72 + kck]) = kreg1;
        #pragma unroll
        for (int d = 0; d < 8; d++) {      // V transposed, packed b32 (conflict-free)
            uint32_t pk = (uint32_t)(ushort)vreg0[d] | ((uint32_t)(ushort)vreg1[d] << 16);
            *(uint32_t*)(&Vts[buf][(dvc * 8 + d) * 72 + kvp * 2]) = pk;
        }
    };

    int qi = qa, q0 = qa * 64;
    short8_t qf[2];
    #pragma unroll
    for (int kc = 0; kc < 2; kc++)
        qf[kc] = *(const short8_t*)(Qb + (size_t)(q0 + w * 16 + m) * DMODEL + kc * 32 + g * 8);

    f32x4 acc_o[4] = {};                   // O[q 16][dv 64] per wave
    float mrun = -1e30f, lrun = 0.f;
    ushort* Pw = Psh[w];                   // wave-private P region

    auto WRITE_O = [&]() {
        #pragma unroll
        for (int r = 0; r < 4; r++) {
            float linv = 1.f / __shfl(lrun, g * 4 + r);
            int qrow = q0 + w * 16 + g * 4 + r;
            #pragma unroll
            for (int dt = 0; dt < 4; dt++)
                Ob[(size_t)qrow * DMODEL + dt * 16 + m] = f2bf(acc_o[dt][r] * linv);
        }
    };
    auto TILE = [&](int t) { return (t < na) ? t : t - na; };

    LOADKV(TILE(0) * 64);                  // prologue: tile 0 -> regs -> buf0, tile 1 -> regs
    WRITEKV(0);
    LOADKV(TILE(1) * 64);

    for (int tt = 0; tt < 33; ++tt) {
        if (tt == na) {                    // half boundary: finish A, start B
            WRITE_O();
            #pragma unroll
            for (int dt = 0; dt < 4; dt++) acc_o[dt] = f32x4{0.f, 0.f, 0.f, 0.f};
            mrun = -1e30f; lrun = 0.f;
            qi = 31 - qa; q0 = qi * 64;
            #pragma unroll
            for (int kc = 0; kc < 2; kc++)
                qf[kc] = *(const short8_t*)(Qb + (size_t)(q0 + w * 16 + m) * DMODEL + kc * 32 + g * 8);
        }
        const int t = TILE(tt);
        const int kv0 = t * 64;
        const bool need_mask = (t == qi);  // only the diagonal tile is masked
        const int cur = tt & 1;

        __syncthreads();                   // buf cur writes visible; buf cur^1 reads complete
        if (tt + 1 < 33) {
            WRITEKV(cur ^ 1);              // stage tile tt+1 (regs -> LDS), overlaps compute
            if (tt + 2 < 33) LOADKV(TILE(tt + 2) * 64);
        }

        // S^T = K * Q^T : lane holds S^T[kv = kvT*16 + g*4 + r][q = m]  (exp2-domain scores)
        f32x4 s[4] = {};
        __builtin_amdgcn_s_setprio(1);
        #pragma unroll
        for (int kvT = 0; kvT < 4; kvT++)
            #pragma unroll
            for (int kc = 0; kc < 2; kc++) {
                short8_t kf = *(const short8_t*)(&Ksh[cur][(kvT * 16 + m) * 72 + kc * 32 + g * 8]);
                s[kvT] = __builtin_amdgcn_mfma_f32_16x16x32_bf16(kf, qf[kc], s[kvT], 0, 0, 0);
            }
        __builtin_amdgcn_s_setprio(0);

        // causal mask (diagonal tile only) + tile max
        const int qg = q0 + w * 16 + m;
        float pmax = -1e30f;
        #pragma unroll
        for (int kvT = 0; kvT < 4; kvT++)
            #pragma unroll
            for (int r = 0; r < 4; r++) {
                float val = s[kvT][r];
                if (need_mask) {
                    int kv_g = kv0 + kvT * 16 + g * 4 + r;
                    if (kv_g > qg) val = -1e30f;
                }
                s[kvT][r] = val;
                pmax = fmaxf(pmax, val);
            }
        pmax = fmaxf(pmax, __shfl_xor(pmax, 16));
        pmax = fmaxf(pmax, __shfl_xor(pmax, 32));
        if (!__all(pmax <= mrun + 8.f)) {  // T13 defer-max: rescale only on real max growth
            float mnew = fmaxf(mrun, pmax);
            float fac = exp2f(mrun - mnew);
            mrun = mnew;
            lrun *= fac;
            #pragma unroll
            for (int r = 0; r < 4; r++) {
                float f = __shfl(fac, g * 4 + r);
                #pragma unroll
                for (int dt = 0; dt < 4; dt++) acc_o[dt][r] *= f;
            }
        }
        float psum = 0.f;
        #pragma unroll
        for (int kvT = 0; kvT < 4; kvT++)
            #pragma unroll
            for (int r = 0; r < 4; r++) {
                float p = exp2f(s[kvT][r] - mrun);   // bounded by 2^8 under defer-max
                s[kvT][r] = p;
                psum += p;
            }
        psum += __shfl_xor(psum, 16);
        psum += __shfl_xor(psum, 32);
        lrun += psum;

        // P (bf16) -> wave-private LDS (same-wave write->read: lgkmcnt-ordered, no barrier)
        #pragma unroll
        for (int kvT = 0; kvT < 4; kvT++) {
            uint32_t lo = (uint32_t)f2bf(s[kvT][0]) | ((uint32_t)f2bf(s[kvT][1]) << 16);
            uint32_t hi = (uint32_t)f2bf(s[kvT][2]) | ((uint32_t)f2bf(s[kvT][3]) << 16);
            uint2 pk; pk.x = lo; pk.y = hi;
            *(uint2*)(Pw + m * 72 + kvT * 16 + g * 4) = pk;
        }

        // O += P * V
        short8_t pf[2];
        #pragma unroll
        for (int kc = 0; kc < 2; kc++)
            pf[kc] = *(const short8_t*)(Pw + m * 72 + kc * 32 + g * 8);
        __builtin_amdgcn_s_setprio(1);
        #pragma unroll
        for (int dt = 0; dt < 4; dt++)
            #pragma unroll
            for (int kc = 0; kc < 2; kc++) {
                short8_t vf = *(const short8_t*)(&Vts[cur][(dt * 16 + m) * 72 + kc * 32 + g * 8]);
                acc_o[dt] = __builtin_amdgcn_mfma_f32_16x16x32_bf16(pf[kc], vf, acc_o[dt], 0, 0, 0);
            }
        __builtin_amdgcn_s_setprio(0);
    }
    WRITE_O();
}

// ---------------- launch ----------------
extern "C" void kernel_launch(void* const* d_in, const int* in_sizes, int n_in,
                              void* d_out, int out_size, void* d_ws, size_t ws_size,
                              hipStream_t stream) {
    (void)in_sizes; (void)n_in; (void)out_size; (void)ws_size;
    const float* q  = (const float*)d_in[0];
    const float* k  = (const float*)d_in[1];
    const float* v  = (const float*)d_in[2];
    // d_in[3] = mask (causal tril) -- implemented analytically
    const float* Wq = (const float*)d_in[4];
    const float* Wk = (const float*)d_in[5];
    const float* Wv = (const float*)d_in[6];
    const float* Wo = (const float*)d_in[7];

    ushort* ws = (ushort*)d_ws;
    const size_t MK = (size_t)MTOT * DMODEL;    // 4194304 elems
    const size_t NK = (size_t)DMODEL * DMODEL;  // 1048576 elems
    ushort* qkvb = ws;                    // bf16 q,k,v        [3*MK]   (24 MB)
    ushort* wt   = ws + 3 * MK;           // bf16 W^T x4       [4*NK]   ( 8 MB)
    ushort* qkvp = ws + 3 * MK + 4 * NK;  // bf16 Q,K,V proj   [3*MK]   (24 MB)
    ushort* Op   = ws;                    // attn out reuses qkvb region ( 8 MB)
    // total ws footprint: 56 MB

    convert_qkv_kernel<<<dim3(12288), dim3(256), 0, stream>>>(q, k, v, qkvb);
    convw_kernel<<<dim3(32, 32, 4), dim3(32, 8), 0, stream>>>(Wq, Wk, Wv, Wo, wt);
    gemm_bt_kernel<false><<<dim3(32, 8, 3), dim3(256), 0, stream>>>(qkvb, wt, (void*)qkvp,
                                                                    MTOT, DMODEL, DMODEL);
    attn_kernel<<<dim3(16, 32), dim3(256), 0, stream>>>(qkvp, qkvp + MK, qkvp + 2 * MK, Op);
    gemm_bt_kernel<true><<<dim3(32, 8, 1), dim3(256), 0, stream>>>(Op, wt + 3 * NK, d_out,
                                                                   MTOT, DMODEL, DMODEL);
}

// Round 6
// 133.856 us; speedup vs baseline: 1.2613x; 1.0325x over previous
//
#include <hip/hip_runtime.h>
#include <hip/hip_bf16.h>
#include <stdint.h>

// Problem constants (fixed by setup_inputs)
#define T_SEQ  2048
#define DMODEL 1024
#define NBATCH 2
#define NHEAD  16
#define DHEAD  64
#define MTOT   (NBATCH * T_SEQ)   // 4096 rows for all projection GEMMs

typedef __attribute__((ext_vector_type(8))) short short8_t;  // 8 bf16 (4 VGPRs) MFMA A/B frag
typedef __attribute__((ext_vector_type(4))) float f32x4;     // MFMA C/D frag
typedef __attribute__((ext_vector_type(2))) __bf16 bhalf2_t;
typedef __attribute__((ext_vector_type(4))) uint32_t uint4_t;

typedef const __attribute__((address_space(1))) void* gas_t;
typedef __attribute__((address_space(3))) void* las_t;

// Native f32->bf16 (gfx950 v_cvt_pk_bf16_f32, RNE). m240: scalar casts, NOT bit-twiddle/asm.
__device__ __forceinline__ ushort f2bf(float f) {
    return __builtin_bit_cast(unsigned short, (__bf16)f);
}
__device__ __forceinline__ uint32_t pk_bf16(float a, float b) {  // -> one v_cvt_pk_bf16_f32
    bhalf2_t t; t[0] = (__bf16)a; t[1] = (__bf16)b;
    return __builtin_bit_cast(uint32_t, t);
}

// ---------------- fp32 -> bf16 convert of q,k,v into one contiguous [3][4096][1024] ----------------
__global__ __launch_bounds__(256) void convert_qkv_kernel(
        const float* __restrict__ q, const float* __restrict__ k,
        const float* __restrict__ v, ushort* __restrict__ outb) {
    const size_t per = (size_t)MTOT * DMODEL / 4;           // float4s per tensor = 1048576
    size_t idx = (size_t)blockIdx.x * 256 + threadIdx.x;
    int t = (int)(idx / per);
    size_t i = idx - (size_t)t * per;
    const float4* src = (const float4*)(t == 0 ? q : (t == 1 ? k : v));
    float4 val = src[i];
    uint2 o;
    o.x = pk_bf16(val.x, val.y);
    o.y = pk_bf16(val.z, val.w);
    ((uint2*)outb)[(size_t)t * per + i] = o;
}

// ---- W fp32 [K][N] -> bf16 transposed [N][K]; Wq gets 1/sqrt(dk)*log2(e) folded in (exp2 domain) --
__global__ __launch_bounds__(256) void convw_kernel(
        const float* __restrict__ Wq, const float* __restrict__ Wk,
        const float* __restrict__ Wv, const float* __restrict__ Wo,
        ushort* __restrict__ wt) {
    __shared__ float tile[32][33];                          // +1 pad: conflict-free transpose
    int z = blockIdx.z;
    const float* W = z == 0 ? Wq : z == 1 ? Wk : z == 2 ? Wv : Wo;
    const float sc = (z == 0) ? 0.18033688011f : 1.0f;      // 0.125 * log2(e)
    ushort* out = wt + (size_t)z * DMODEL * DMODEL;
    int tx = threadIdx.x, ty = threadIdx.y;                 // 32 x 8
    int k0 = blockIdx.x * 32, n0 = blockIdx.y * 32;
    #pragma unroll
    for (int i = 0; i < 4; i++)
        tile[ty + i * 8][tx] = W[(size_t)(k0 + ty + i * 8) * DMODEL + n0 + tx];
    __syncthreads();
    #pragma unroll
    for (int i = 0; i < 4; i++)
        out[(size_t)(n0 + ty + i * 8) * DMODEL + k0 + tx] = f2bf(tile[tx][ty + i * 8] * sc);
}

// ---------------- bf16 GEMM, m97 structure: C[M][N] = A[M][K] * Bt[N][K]^T ----------------
// 128x128 tile, BK=32, 4 waves (2x2), 4x4 16x16x32 MFMA accs per wave, global_load_lds(16B) staging.
template <bool OUT_F32>
__global__ __launch_bounds__(256, 2) void gemm_bt_kernel(
        const ushort* __restrict__ Aall, const ushort* __restrict__ Btall,
        void* __restrict__ Call, int M, int N, int K) {
    const ushort* A  = Aall  + (size_t)blockIdx.z * M * K;
    const ushort* Bt = Btall + (size_t)blockIdx.z * N * K;

    __shared__ ushort As[128 * 32];   // [128 rows][32 k] row-major, 8 KB
    __shared__ ushort Bs[128 * 32];

    const int tid  = threadIdx.x;
    const int lane = tid & 63;
    const int wid  = tid >> 6;
    const int wr = wid >> 1, wc = wid & 1;          // 2x2 wave grid, 64x64 out each
    const int m_base = blockIdx.x * 128;
    const int n_base = blockIdx.y * 128;

    f32x4 acc[4][4] = {};

    const int srow = lane >> 2;                     // staging: 16 rows / chunk
    const int scol = (lane & 3) * 8;                // 4 x 16B per row

    for (int kk = 0; kk < K; kk += 32) {
        __syncthreads();                            // prior tile's reads complete
        #pragma unroll
        for (int i = 0; i < 2; i++) {
            int c = wid * 2 + i;                    // 8 x 1KB chunks each for A and B
            const ushort* ga = A  + (size_t)(m_base + c * 16 + srow) * K + kk + scol;
            const ushort* gb = Bt + (size_t)(n_base + c * 16 + srow) * K + kk + scol;
            __builtin_amdgcn_global_load_lds((gas_t)ga, (las_t)(As + c * 512), 16, 0, 0);
            __builtin_amdgcn_global_load_lds((gas_t)gb, (las_t)(Bs + c * 512), 16, 0, 0);
        }
        __syncthreads();                            // drains vmcnt -> staged data visible
        short8_t a[4], b[4];
        #pragma unroll
        for (int mt = 0; mt < 4; mt++)
            a[mt] = *(const short8_t*)(As + (wr * 64 + mt * 16 + (lane & 15)) * 32 + (lane >> 4) * 8);
        #pragma unroll
        for (int nt = 0; nt < 4; nt++)
            b[nt] = *(const short8_t*)(Bs + (wc * 64 + nt * 16 + (lane & 15)) * 32 + (lane >> 4) * 8);
        #pragma unroll
        for (int mt = 0; mt < 4; mt++)
            #pragma unroll
            for (int nt = 0; nt < 4; nt++)
                acc[mt][nt] = __builtin_amdgcn_mfma_f32_16x16x32_bf16(a[mt], b[nt], acc[mt][nt], 0, 0, 0);
    }

    // Epilogue: D layout col = lane&15, row = (lane>>4)*4 + r  [verified m89/m91]
    const int row0 = m_base + wr * 64 + (lane >> 4) * 4;
    const int col0 = n_base + wc * 64 + (lane & 15);
    if constexpr (OUT_F32) {
        float* C = (float*)Call + (size_t)blockIdx.z * M * N;
        #pragma unroll
        for (int mt = 0; mt < 4; mt++)
            #pragma unroll
            for (int nt = 0; nt < 4; nt++)
                #pragma unroll
                for (int r = 0; r < 4; r++)
                    C[(size_t)(row0 + mt * 16 + r) * N + col0 + nt * 16] = acc[mt][nt][r];
    } else {
        ushort* C = (ushort*)Call + (size_t)blockIdx.z * M * N;
        #pragma unroll
        for (int mt = 0; mt < 4; mt++)
            #pragma unroll
            for (int nt = 0; nt < 4; nt++)
                #pragma unroll
                for (int r = 0; r < 4; r++)
                    C[(size_t)(row0 + mt * 16 + r) * N + col0 + nt * 16] = f2bf(acc[mt][nt][r]);
    }
}

// ---------------- causal flash attention, balanced pairs + dbuf (1 barrier/tile) ----------------
// grid = (16 pairs, 32 b*h) = 512 blocks, 4 waves. Block does q-blocks qa and 31-qa (QBLK=64):
// exactly 33 KV-tiles. Each wave owns 16 q-rows. K/V double-buffered in LDS (pad-72):
// iter tt = {barrier; ds-write tile tt+1; global-load tile tt+2; compute tile tt}.
// exp2-domain softmax (scale*log2e folded into Wq), T13 defer-max, T5 setprio,
// native cvt_pk for all f32->bf16, v_perm for the V-transpose interleave.
__global__ __launch_bounds__(256, 2) void attn_kernel(
        const ushort* __restrict__ Qp, const ushort* __restrict__ Kp,
        const ushort* __restrict__ Vp, ushort* __restrict__ Op) {
    __shared__ __attribute__((aligned(16))) ushort Ksh[2][64 * 72];  // [kv][dk], 144B rows
    __shared__ __attribute__((aligned(16))) ushort Vts[2][64 * 72];  // [dv][kv] transposed
    __shared__ __attribute__((aligned(16))) ushort Psh[4][16 * 72];  // per-wave P [16 q][64 kv]

    const int tid = threadIdx.x, lane = tid & 63, w = tid >> 6;
    const int g = lane >> 4;               // 4 lane-groups of 16
    const int m = lane & 15;
    const int bh = blockIdx.y;
    const int b = bh >> 4, h = bh & 15;

    const ushort* Qb = Qp + (size_t)(b * T_SEQ) * DMODEL + h * DHEAD;
    const ushort* Kb = Kp + (size_t)(b * T_SEQ) * DMODEL + h * DHEAD;
    const ushort* Vb = Vp + (size_t)(b * T_SEQ) * DMODEL + h * DHEAD;
    ushort* Ob = Op + (size_t)(b * T_SEQ) * DMODEL + h * DHEAD;

    const int qa = blockIdx.x;             // first (light) q-block
    const int na = qa + 1;                 // tiles for half A; half B: 31-qa -> 32-qa tiles

    // staging decomposition (256 threads)
    const int kr  = tid >> 3, kck = (tid & 7) * 8;   // K: rows kr, kr+32; 16B col chunk
    const int kvp = tid & 31, dvc = tid >> 5;        // V: kv pair, dv 8-chunk

    short8_t kreg0, kreg1, vreg0, vreg1;             // prefetched K/V tile (16 VGPRs)
    auto LOADKV = [&](int kv0) {
        kreg0 = *(const short8_t*)(Kb + (size_t)(kv0 + kr) * DMODEL + kck);
        kreg1 = *(const short8_t*)(Kb + (size_t)(kv0 + kr + 32) * DMODEL + kck);
        const ushort* vsrc = Vb + (size_t)(kv0 + kvp * 2) * DMODEL + dvc * 8;
        vreg0 = *(const short8_t*)(vsrc);
        vreg1 = *(const short8_t*)(vsrc + DMODEL);
    };
    auto WRITEKV = [&](int buf) {
        *(short8_t*)(&Ksh[buf][kr * 72 + kck]) = kreg0;
        *(short8_t*)(&Ksh[buf][(kr + 32) * 72 + kck]) = kreg1;
        // V transposed, interleave via v_perm_b32 (byte sel: {v1.b1,v1.b0,v0.b1,v0.b0})
        uint4_t a = __builtin_bit_cast(uint4_t, vreg0);
        uint4_t c = __builtin_bit_cast(uint4_t, vreg1);
        #pragma unroll
        for (int j = 0; j < 4; j++) {
            uint32_t pk0 = __builtin_amdgcn_perm(c[j], a[j], 0x05040100u);  // elem 2j
            uint32_t pk1 = __builtin_amdgcn_perm(c[j], a[j], 0x07060302u);  // elem 2j+1
            *(uint32_t*)(&Vts[buf][(dvc * 8 + 2 * j) * 72 + kvp * 2]) = pk0;
            *(uint32_t*)(&Vts[buf][(dvc * 8 + 2 * j + 1) * 72 + kvp * 2]) = pk1;
        }
    };

    int qi = qa, q0 = qa * 64;
    short8_t qf[2];
    #pragma unroll
    for (int kc = 0; kc < 2; kc++)
        qf[kc] = *(const short8_t*)(Qb + (size_t)(q0 + w * 16 + m) * DMODEL + kc * 32 + g * 8);

    f32x4 acc_o[4] = {};                   // O[q 16][dv 64] per wave
    float mrun = -1e30f, lrun = 0.f;
    ushort* Pw = Psh[w];                   // wave-private P region

    auto WRITE_O = [&]() {
        #pragma unroll
        for (int r = 0; r < 4; r++) {
            float linv = __builtin_amdgcn_rcpf(__shfl(lrun, g * 4 + r));
            int qrow = q0 + w * 16 + g * 4 + r;
            #pragma unroll
            for (int dt = 0; dt < 4; dt++)
                Ob[(size_t)qrow * DMODEL + dt * 16 + m] = f2bf(acc_o[dt][r] * linv);
        }
    };
    auto TILE = [&](int t) { return (t < na) ? t : t - na; };

    LOADKV(TILE(0) * 64);                  // prologue: tile 0 -> regs -> buf0, tile 1 -> regs
    WRITEKV(0);
    LOADKV(TILE(1) * 64);

    for (int tt = 0; tt < 33; ++tt) {
        if (tt == na) {                    // half boundary: finish A, start B
            WRITE_O();
            #pragma unroll
            for (int dt = 0; dt < 4; dt++) acc_o[dt] = f32x4{0.f, 0.f, 0.f, 0.f};
            mrun = -1e30f; lrun = 0.f;
            qi = 31 - qa; q0 = qi * 64;
            #pragma unroll
            for (int kc = 0; kc < 2; kc++)
                qf[kc] = *(const short8_t*)(Qb + (size_t)(q0 + w * 16 + m) * DMODEL + kc * 32 + g * 8);
        }
        const int t = TILE(tt);
        const int kv0 = t * 64;
        const bool need_mask = (t == qi);  // only the diagonal tile is masked
        const int cur = tt & 1;

        __syncthreads();                   // buf cur writes visible; buf cur^1 reads complete
        if (tt + 1 < 33) {
            WRITEKV(cur ^ 1);              // stage tile tt+1 (regs -> LDS), overlaps compute
            if (tt + 2 < 33) LOADKV(TILE(tt + 2) * 64);
        }

        // S^T = K * Q^T : lane holds S^T[kv = kvT*16 + g*4 + r][q = m]  (exp2-domain scores)
        f32x4 s[4] = {};
        __builtin_amdgcn_s_setprio(1);
        #pragma unroll
        for (int kvT = 0; kvT < 4; kvT++)
            #pragma unroll
            for (int kc = 0; kc < 2; kc++) {
                short8_t kf = *(const short8_t*)(&Ksh[cur][(kvT * 16 + m) * 72 + kc * 32 + g * 8]);
                s[kvT] = __builtin_amdgcn_mfma_f32_16x16x32_bf16(kf, qf[kc], s[kvT], 0, 0, 0);
            }
        __builtin_amdgcn_s_setprio(0);

        // causal mask (diagonal tile only) + tile max
        const int qg = q0 + w * 16 + m;
        float pmax = -1e30f;
        #pragma unroll
        for (int kvT = 0; kvT < 4; kvT++)
            #pragma unroll
            for (int r = 0; r < 4; r++) {
                float val = s[kvT][r];
                if (need_mask) {
                    int kv_g = kv0 + kvT * 16 + g * 4 + r;
                    if (kv_g > qg) val = -1e30f;
                }
                s[kvT][r] = val;
                pmax = fmaxf(pmax, val);
            }
        pmax = fmaxf(pmax, __shfl_xor(pmax, 16));
        pmax = fmaxf(pmax, __shfl_xor(pmax, 32));
        if (!__all(pmax <= mrun + 8.f)) {  // T13 defer-max: rescale only on real max growth
            float mnew = fmaxf(mrun, pmax);
            float fac = exp2f(mrun - mnew);
            mrun = mnew;
            lrun *= fac;
            #pragma unroll
            for (int r = 0; r < 4; r++) {
                float f = __shfl(fac, g * 4 + r);
                #pragma unroll
                for (int dt = 0; dt < 4; dt++) acc_o[dt][r] *= f;
            }
        }
        float psum = 0.f;
        #pragma unroll
        for (int kvT = 0; kvT < 4; kvT++)
            #pragma unroll
            for (int r = 0; r < 4; r++) {
                float p = exp2f(s[kvT][r] - mrun);   // bounded by 2^8 under defer-max
                s[kvT][r] = p;
                psum += p;
            }
        psum += __shfl_xor(psum, 16);
        psum += __shfl_xor(psum, 32);
        lrun += psum;

        // P (bf16, native cvt_pk) -> wave-private LDS (same-wave write->read, lgkmcnt-ordered)
        #pragma unroll
        for (int kvT = 0; kvT < 4; kvT++) {
            uint2 pk;
            pk.x = pk_bf16(s[kvT][0], s[kvT][1]);
            pk.y = pk_bf16(s[kvT][2], s[kvT][3]);
            *(uint2*)(Pw + m * 72 + kvT * 16 + g * 4) = pk;
        }

        // O += P * V
        short8_t pf[2];
        #pragma unroll
        for (int kc = 0; kc < 2; kc++)
            pf[kc] = *(const short8_t*)(Pw + m * 72 + kc * 32 + g * 8);
        __builtin_amdgcn_s_setprio(1);
        #pragma unroll
        for (int dt = 0; dt < 4; dt++)
            #pragma unroll
            for (int kc = 0; kc < 2; kc++) {
                short8_t vf = *(const short8_t*)(&Vts[cur][(dt * 16 + m) * 72 + kc * 32 + g * 8]);
                acc_o[dt] = __builtin_amdgcn_mfma_f32_16x16x32_bf16(pf[kc], vf, acc_o[dt], 0, 0, 0);
            }
        __builtin_amdgcn_s_setprio(0);
    }
    WRITE_O();
}

// ---------------- launch ----------------
extern "C" void kernel_launch(void* const* d_in, const int* in_sizes, int n_in,
                              void* d_out, int out_size, void* d_ws, size_t ws_size,
                              hipStream_t stream) {
    (void)in_sizes; (void)n_in; (void)out_size; (void)ws_size;
    const float* q  = (const float*)d_in[0];
    const float* k  = (const float*)d_in[1];
    const float* v  = (const float*)d_in[2];
    // d_in[3] = mask (causal tril) -- implemented analytically
    const float* Wq = (const float*)d_in[4];
    const float* Wk = (const float*)d_in[5];
    const float* Wv = (const float*)d_in[6];
    const float* Wo = (const float*)d_in[7];

    ushort* ws = (ushort*)d_ws;
    const size_t MK = (size_t)MTOT * DMODEL;    // 4194304 elems
    const size_t NK = (size_t)DMODEL * DMODEL;  // 1048576 elems
    ushort* qkvb = ws;                    // bf16 q,k,v        [3*MK]   (24 MB)
    ushort* wt   = ws + 3 * MK;           // bf16 W^T x4       [4*NK]   ( 8 MB)
    ushort* qkvp = ws + 3 * MK + 4 * NK;  // bf16 Q,K,V proj   [3*MK]   (24 MB)
    ushort* Op   = ws;                    // attn out reuses qkvb region ( 8 MB)
    // total ws footprint: 56 MB

    convert_qkv_kernel<<<dim3(12288), dim3(256), 0, stream>>>(q, k, v, qkvb);
    convw_kernel<<<dim3(32, 32, 4), dim3(32, 8), 0, stream>>>(Wq, Wk, Wv, Wo, wt);
    gemm_bt_kernel<false><<<dim3(32, 8, 3), dim3(256), 0, stream>>>(qkvb, wt, (void*)qkvp,
                                                                    MTOT, DMODEL, DMODEL);
    attn_kernel<<<dim3(16, 32), dim3(256), 0, stream>>>(qkvp, qkvp + MK, qkvp + 2 * MK, Op);
    gemm_bt_kernel<true><<<dim3(32, 8, 1), dim3(256), 0, stream>>>(Op, wt + 3 * NK, d_out,
                                                                   MTOT, DMODEL, DMODEL);
}